// Round 21
// baseline (569.538 us; speedup 1.0000x reference)
//
#include <hip/hip_runtime.h>
#include <math.h>

#define CH 128
#define KSEL 512
#define CAP 4096
#define TOT 2048   // 4*KSEL
#define TS 32      // NMS tile
#define NEG_INF (-__builtin_inff())

typedef short s8v __attribute__((ext_vector_type(8)));   // 8 bf16 (4 VGPRs)
typedef float f4v __attribute__((ext_vector_type(4)));   // MFMA acc

__device__ __forceinline__ float gelu_exact(float v) {
    return v * 0.5f * (1.0f + erff(v * 0.70710678118654752440f));
}

// exact 3-plane bf16 split: v = bf(h) + bf(m) + bf(l) + O(2^-24 v)
// R15 lesson: outputs are rank-ordered; rel accuracy must stay ~1e-8
// (6-term split3 passes; 3-term split2 at ~1e-5 scrambles ranks).
__device__ __forceinline__ void split3(float v, unsigned short& h,
                                       unsigned short& m, unsigned short& l)
{
    union { float f; unsigned u; } a; a.f = v;
    unsigned rh = a.u + 0x7FFFu + ((a.u >> 16) & 1u);
    h = (unsigned short)(rh >> 16);
    union { unsigned u; float f; } fh; fh.u = rh & 0xFFFF0000u;
    float r1 = v - fh.f;
    union { float f; unsigned u; } bu; bu.f = r1;
    unsigned rm = bu.u + 0x7FFFu + ((bu.u >> 16) & 1u);
    m = (unsigned short)(rm >> 16);
    union { unsigned u; float f; } fm2; fm2.u = rm & 0xFFFF0000u;
    float r2 = r1 - fm2.f;
    union { float f; unsigned u; } cu; cu.f = r2;
    unsigned rl = cu.u + 0x7FFFu + ((cu.u >> 16) & 1u);
    l = (unsigned short)(rl >> 16);
}

// ---------------- W1 -> 3-plane bf16 A-fragments (verbatim, verified) ----------------
__global__ __launch_bounds__(256) void wconv_kernel(const float* __restrict__ w1,
                                                    unsigned short* __restrict__ wfrag)
{
    for (int e = blockIdx.x * 256 + threadIdx.x; e < 49152; e += gridDim.x * 256) {
        int fid = e >> 9;
        int r = e & 511;
        int lane = r >> 3;
        int el = r & 7;
        int plane = fid % 3;
        int fq = fid / 3;
        int kc = fq >> 3, ot = fq & 7;
        int och = ot * 16 + (lane & 15);
        int k = kc * 32 + ((lane >> 4) << 3) + el;
        unsigned short h, m, l;
        split3(w1[och * CH + k], h, m, l);
        wfrag[e] = (plane == 0) ? h : (plane == 1) ? m : l;
    }
}

// ---------------- reliability head via split-bf16 MFMA ----------------
// 1024 thr / 16 waves (4 waves/SIMD; R20 proved 96 regs/wave fits).
// R20's 2x overfetch (16-lane scalar loads = 64B segments) is fixed by
// LDS-staging X per kc: block stages 256px x 32ch (32KB) with coalesced
// 256B wave-loads; register prefetch of kc+1 hides HBM latency under
// compute; lanes read B-operands from Xs[32][257] (odd pitch -> 2-way
// bank access = free). Numerics bit-identical to R20 (same values).
__global__ __launch_bounds__(1024) void rel_mfma_kernel(
    const float* __restrict__ fm0, const float* __restrict__ fm1,
    const float* __restrict__ fm2, const float* __restrict__ fm3,
    const unsigned short* __restrict__ wfrag,
    const float* __restrict__ b1, const float* __restrict__ w2,
    const float* __restrict__ b2, float* __restrict__ rel)
{
    __shared__ uint4 WfQ[6144];            // 96 KB W fragments
    __shared__ float Xs[32][257];          // 32.9 KB staged X (kc slice)
    __shared__ float w2s[128], b1s[128];
    unsigned short* Wf = (unsigned short*)WfQ;

    const int tid = threadIdx.x;
    {
        const uint4* src = (const uint4*)wfrag;
        for (int i = tid; i < 6144; i += 1024) WfQ[i] = src[i];
    }
    if (tid < 128) { w2s[tid] = w2[tid]; b1s[tid] = b1[tid]; }
    __syncthreads();

    const float* fms[4] = {fm0, fm1, fm2, fm3};
    // 256-px tiles: s0 2048, s1 512, s2 128, s3 32 -> total 2720
    const int pre1 = 2048, pre2 = 2560, pre3 = 2688;
    const int relo[4] = {0, 524288, 655360, 688128};
    const float b2v = b2[0];

    const int lane = tid & 63;
    const int j = lane & 15;               // MFMA col / px within wave subtile
    const int g8 = (lane >> 4) << 3;       // k sub-base within 32-chunk
    const int w = tid >> 6;                // wave id 0..15
    const int spx = tid & 255;             // staging px (coalesced)
    const int sc0 = tid >> 8;              // staging channel base 0..3

    for (int T = blockIdx.x; T < 2720; T += gridDim.x) {
        int s = (T >= pre1) + (T >= pre2) + (T >= pre3);
        int t2 = T - ((s == 0) ? 0 : (s == 1) ? pre1 : (s == 2) ? pre2 : pre3);
        int Wd = 512 >> s, HW = Wd * Wd;
        int p0 = t2 * 256;                 // HW % 256 == 0 -> no b straddle
        int b = (p0 >= HW) ? 1 : 0;
        int pb = p0 - b * HW;
        int pw = pb + w * 16;              // wave's 16-px base
        const float* fp = fms[s] + (size_t)b * CH * HW;
        int rr = Wd >> 6; if (rr < 1) rr = 1;

        const float* xg = fp + pb + spx;   // staging source (coalesced in spx)

        float rs[8];
        #pragma unroll
        for (int p = 0; p < 8; ++p)
            rs[p] = xg[(size_t)(sc0 + (p << 2)) * HW];

        f4v acc[8];
        #pragma unroll
        for (int ot = 0; ot < 8; ++ot) {
            acc[ot][0] = 0.f; acc[ot][1] = 0.f; acc[ot][2] = 0.f; acc[ot][3] = 0.f;
        }

        #pragma unroll 1   // REAL loop: prevents load hoisting -> no spill (R14)
        for (int kc = 0; kc < 4; ++kc) {
            __syncthreads();               // prior compute done -> safe to overwrite Xs
            #pragma unroll
            for (int p = 0; p < 8; ++p)
                Xs[sc0 + (p << 2)][spx] = rs[p];
            float rs2[8];
            if (kc < 3) {
                #pragma unroll
                for (int p = 0; p < 8; ++p)
                    rs2[p] = xg[(size_t)((kc + 1) * 32 + sc0 + (p << 2)) * HW];
            }
            __syncthreads();               // Xs ready

            float xv[8];
            #pragma unroll
            for (int e = 0; e < 8; ++e)
                xv[e] = Xs[g8 + e][w * 16 + j];

            s8v bh, bm, bl;
            #pragma unroll
            for (int e = 0; e < 8; ++e) {
                unsigned short h, m, l;
                split3(xv[e], h, m, l);
                bh[e] = (short)h; bm[e] = (short)m; bl[e] = (short)l;
            }
            #pragma unroll
            for (int ot = 0; ot < 8; ++ot) {
                const unsigned short* fb = Wf + (((kc << 3) + ot) * 3) * 512 + (lane << 3);
                s8v ah = *(const s8v*)fb;
                s8v am = *(const s8v*)(fb + 512);
                s8v al = *(const s8v*)(fb + 1024);
                acc[ot] = __builtin_amdgcn_mfma_f32_16x16x32_bf16(ah, bh, acc[ot], 0, 0, 0);
                acc[ot] = __builtin_amdgcn_mfma_f32_16x16x32_bf16(ah, bm, acc[ot], 0, 0, 0);
                acc[ot] = __builtin_amdgcn_mfma_f32_16x16x32_bf16(am, bh, acc[ot], 0, 0, 0);
                acc[ot] = __builtin_amdgcn_mfma_f32_16x16x32_bf16(am, bm, acc[ot], 0, 0, 0);
                acc[ot] = __builtin_amdgcn_mfma_f32_16x16x32_bf16(ah, bl, acc[ot], 0, 0, 0);
                acc[ot] = __builtin_amdgcn_mfma_f32_16x16x32_bf16(al, bh, acc[ot], 0, 0, 0);
            }

            if (kc < 3) {
                #pragma unroll
                for (int p = 0; p < 8; ++p) rs[p] = rs2[p];
            }
        }

        // epilogue: C/D map (HW-verified): col = lane&15 (px), row = (lane>>4)*4 + r
        float part = 0.f;
        #pragma unroll
        for (int ot = 0; ot < 8; ++ot) {
            #pragma unroll
            for (int r = 0; r < 4; ++r) {
                int och = ot * 16 + ((lane >> 4) << 2) + r;
                part += w2s[och] * gelu_exact(acc[ot][r] + b1s[och]);
            }
        }
        part += __shfl_xor(part, 16);
        part += __shfl_xor(part, 32);
        if (lane < 16) {
            int p = pw + lane;
            int y = p / Wd, x = p - y * Wd;
            bool inte = (y >= rr) && (y < Wd - rr) && (x >= rr) && (x < Wd - rr);
            rel[relo[s] + b * HW + p] = inte ? (part + b2v) : NEG_INF;
        }
    }
}

// ---------------- multi-scale NMS block decode ----------------
// tiles/scale: s0 512, s1 128, s2 32, s3 8 -> 680 blocks per stage
__device__ __forceinline__ void nms_decode(int blk, int& s, int& b, int& ty, int& tx,
                                           int& Wd, int& HW, int& r, int& ro)
{
    s = (blk >= 512) + (blk >= 640) + (blk >= 672);
    int t2 = blk - ((s == 0) ? 0 : (s == 1) ? 512 : (s == 2) ? 640 : 672);
    Wd = 512 >> s; HW = Wd * Wd;
    int tpb = (Wd / TS) * (Wd / TS);
    b = t2 / tpb;
    int t = t2 - b * tpb;
    ty = t / (Wd / TS); tx = t - ty * (Wd / TS);
    r = Wd >> 6; if (r < 1) r = 1;
    ro = (s == 0) ? 0 : (s == 1) ? 524288 : (s == 2) ? 655360 : 688128;
}

// init: mask = (rel == maxpool_r(rel))  [R16-verified]
__global__ __launch_bounds__(256) void nms_init_all(
    const float* __restrict__ rel, float* __restrict__ mask)
{
    int s, b, ty, tx, W, HW, r, ro;
    nms_decode(blockIdx.x, s, b, ty, tx, W, HW, r, ro);
    int H = W;
    int L = TS + 2 * r;
    __shared__ float wtile[48][49];
    __shared__ float t1[48][49];
    const float* wp = rel + ro + (size_t)b * HW;
    for (int idx = threadIdx.x; idx < L * L; idx += 256) {
        int i = idx / L, j = idx - i * L;
        int gy = min(max(ty * TS - r + i, 0), H - 1);
        int gx = min(max(tx * TS - r + j, 0), W - 1);
        wtile[i][j] = wp[gy * W + gx];
    }
    __syncthreads();
    for (int idx = threadIdx.x; idx < L * TS; idx += 256) {
        int i = idx / TS, j = idx - i * TS;
        float m = wtile[i][j];
        for (int d = 1; d <= 2 * r; ++d) m = fmaxf(m, wtile[i][j + d]);
        t1[i][j] = m;
    }
    __syncthreads();
    for (int idx = threadIdx.x; idx < TS * TS; idx += 256) {
        int i = idx / TS, j = idx - i * TS;
        float m = t1[i][j];
        for (int d = 1; d <= 2 * r; ++d) m = fmaxf(m, t1[i + d][j]);
        mask[ro + (size_t)b * HW + (ty * TS + i) * W + (tx * TS + j)] =
            (wtile[i + r][j + r] == m) ? 1.0f : 0.0f;
    }
}

// fused iterA+iterB (R16-verified); optional compact
__global__ __launch_bounds__(256) void nms_fused_all(
    const float* __restrict__ rel, float* __restrict__ mask, int do_compact,
    float* __restrict__ lval, int* __restrict__ lidx, int* __restrict__ counts)
{
    int s, b, ty, tx, W, HW, r, ro;
    nms_decode(blockIdx.x, s, b, ty, tx, W, HW, r, ro);
    int H = W;
    int L = TS + 4 * r;                 // <= 64
    int gy0 = ty * TS - 2 * r, gx0 = tx * TS - 2 * r;
    __shared__ float A[64][65], B[64][65], C[64][65];
    const float* mp = mask + ro + (size_t)b * HW;
    const float* rp = rel + ro + (size_t)b * HW;

    for (int idx = threadIdx.x; idx < L * L; idx += 256) {
        int i = idx / L, j = idx - i * L;
        int gy = min(max(gy0 + i, 0), H - 1);
        int gx = min(max(gx0 + j, 0), W - 1);
        A[i][j] = mp[gy * W + gx];
    }
    __syncthreads();
    int w1c = L - 2 * r;
    for (int idx = threadIdx.x; idx < L * w1c; idx += 256) {
        int i = idx / w1c, j = idx - i * w1c + r;
        float m = A[i][j - r];
        for (int d = 1; d <= 2 * r; ++d) m = fmaxf(m, A[i][j - r + d]);
        B[i][j] = m;
    }
    __syncthreads();
    for (int idx = threadIdx.x; idx < w1c * w1c; idx += 256) {
        int i = idx / w1c + r, j = idx % w1c + r;
        float m = B[i - r][j];
        for (int d = 1; d <= 2 * r; ++d) m = fmaxf(m, B[i - r + d][j]);
        C[i][j] = m;
    }
    float mreg[4];
    #pragma unroll
    for (int k = 0; k < 4; ++k) {
        int idx = threadIdx.x + k * 256;
        int i = idx >> 5, j = idx & 31;
        mreg[k] = A[2 * r + i][2 * r + j];
    }
    __syncthreads();
    for (int idx = threadIdx.x; idx < w1c * w1c; idx += 256) {
        int i = idx / w1c + r, j = idx % w1c + r;
        int gy = min(max(gy0 + i, 0), H - 1);
        int gx = min(max(gx0 + j, 0), W - 1);
        B[i][j] = (C[i][j] > 0.f) ? NEG_INF : rp[gy * W + gx];
    }
    __syncthreads();
    for (int idx = threadIdx.x; idx < w1c * TS; idx += 256) {
        int i = idx / TS + r, j = idx % TS + 2 * r;
        float m = B[i][j - r];
        for (int d = 1; d <= 2 * r; ++d) m = fmaxf(m, B[i][j - r + d]);
        A[i][j] = m;
    }
    __syncthreads();
    #pragma unroll
    for (int k = 0; k < 4; ++k) {
        int idx = threadIdx.x + k * 256;
        int i = idx >> 5, j = idx & 31;
        int ci = 2 * r + i, cj = 2 * r + j;
        float m = A[ci - r][cj];
        for (int d = 1; d <= 2 * r; ++d) m = fmaxf(m, A[ci - r + d][cj]);
        bool supp = C[ci][cj] > 0.f;
        bool newm = (B[ci][cj] == m) && !supp;
        bool fin = (mreg[k] > 0.f) || newm;
        int gy = ty * TS + i, gx = tx * TS + j;
        size_t g = ro + (size_t)b * HW + gy * W + gx;
        if (!do_compact) {
            mask[g] = fin ? 1.f : 0.f;
        } else if (fin) {
            float v = rp[gy * W + gx];
            if (!isinf(v)) {
                int bs = b * 4 + s;
                int slot = atomicAdd(&counts[bs], 1);
                if (slot < CAP) { lval[bs * CAP + slot] = v; lidx[bs * CAP + slot] = gy * W + gx; }
            }
        }
    }
}

// ---------------- per-(b,scale) bitonic sort + top-K ----------------
__global__ __launch_bounds__(1024) void sort_topk_kernel(
    const float* __restrict__ lval, const int* __restrict__ lidx,
    const int* __restrict__ counts, float* __restrict__ tv, int* __restrict__ ti)
{
    __shared__ float sv[CAP];
    __shared__ int   si[CAP];
    int bs = blockIdx.x;
    int M = counts[bs]; if (M > CAP) M = CAP;
    for (int i = threadIdx.x; i < CAP; i += 1024) {
        if (i < M) { sv[i] = lval[bs * CAP + i]; si[i] = lidx[bs * CAP + i]; }
        else       { sv[i] = NEG_INF;            si[i] = 0x7FFFFFFF; }
    }
    __syncthreads();
    for (int k = 2; k <= CAP; k <<= 1) {
        for (int j = k >> 1; j > 0; j >>= 1) {
            for (int t = threadIdx.x; t < CAP; t += 1024) {
                int p = t ^ j;
                if (p > t) {
                    float va = sv[t], vb = sv[p];
                    int   ia = si[t], ib = si[p];
                    bool aBefore = (va > vb) || (va == vb && ia < ib);
                    bool up = ((t & k) == 0);
                    if (up ? !aBefore : aBefore) {
                        sv[t] = vb; sv[p] = va; si[t] = ib; si[p] = ia;
                    }
                }
            }
            __syncthreads();
        }
    }
    for (int j = threadIdx.x; j < KSEL; j += 1024) {
        if (j < M) { tv[bs * KSEL + j] = sv[j]; ti[bs * KSEL + j] = si[j]; }
        else       { tv[bs * KSEL + j] = NEG_INF; ti[bs * KSEL + j] = j - M; }
    }
}

// ---------------- coords + reliability outputs ----------------
__global__ __launch_bounds__(256) void coords_kernel(
    const float* __restrict__ tv, const int* __restrict__ ti, float* __restrict__ out)
{
    int gid = blockIdx.x * blockDim.x + threadIdx.x;
    if (gid >= 8 * KSEL) return;
    int bs = gid / KSEL, k = gid - bs * KSEL;
    int b = bs >> 2, s = bs & 3;
    int W = 512 >> s;
    int idx = ti[gid];
    int y = idx / W, x = idx - y * W;
    float nx = (float)x / (float)(W - 1) * 2.0f - 1.0f;
    float ny = (float)y / (float)(W - 1) * 2.0f - 1.0f;
    int pos = s * KSEL + k;
    out[((size_t)b * TOT + pos) * 2 + 0] = nx;
    out[((size_t)b * TOT + pos) * 2 + 1] = ny;
    out[2 * TOT * 2 + (size_t)b * TOT + pos] = tv[gid];
}

// ---------------- gathered projection head + bilinear combine ----------------
__global__ __launch_bounds__(128) void feats_kernel(
    const float* __restrict__ fm0, const float* __restrict__ fm1,
    const float* __restrict__ fm2, const float* __restrict__ fm3,
    const float* __restrict__ w1, const float* __restrict__ b1,
    const float* __restrict__ w2, const float* __restrict__ b2,
    const int* __restrict__ ti, float* __restrict__ out)
{
    int blk = blockIdx.x;             // (b*4+s)*KSEL + k
    int bs = blk / KSEL, k = blk - bs * KSEL;
    int b = bs >> 2, s = bs & 3;
    int W = 512 >> s, H = W, HW = H * W;
    const float* fm = (s == 0) ? fm0 : (s == 1) ? fm1 : (s == 2) ? fm2 : fm3;

    int idx = ti[bs * KSEL + k];
    int yi0 = idx / W, xi0 = idx - yi0 * W;
    float nx = (float)xi0 / (float)(W - 1) * 2.0f - 1.0f;
    float ny = (float)yi0 / (float)(H - 1) * 2.0f - 1.0f;
    float ix = ((nx + 1.0f) * (float)W - 1.0f) * 0.5f;
    float iy = ((ny + 1.0f) * (float)H - 1.0f) * 0.5f;
    float x0 = floorf(ix), y0 = floorf(iy);
    float x1 = x0 + 1.0f,  y1 = y0 + 1.0f;
    float wx1 = ix - x0, wy1 = iy - y0;

    float xs[4]  = {x0, x1, x0, x1};
    float ysv[4] = {y0, y0, y1, y1};
    float wn[4]  = {(1.0f - wx1) * (1.0f - wy1), wx1 * (1.0f - wy1),
                    (1.0f - wx1) * wy1,          wx1 * wy1};
    int pix[4]; float wv[4];
    #pragma unroll
    for (int n = 0; n < 4; ++n) {
        bool valid = (xs[n] >= 0.0f) && (xs[n] <= (float)(W - 1)) &&
                     (ysv[n] >= 0.0f) && (ysv[n] <= (float)(H - 1));
        int xc = (int)fminf(fmaxf(xs[n], 0.0f), (float)(W - 1));
        int yc = (int)fminf(fmaxf(ysv[n], 0.0f), (float)(H - 1));
        pix[n] = yc * W + xc;
        wv[n] = valid ? wn[n] : 0.0f;
    }

    __shared__ float xls[4][CH];
    __shared__ float hmix[CH];
    int o = threadIdx.x;
    {
        const float* fb_ = fm + ((size_t)b * CH + o) * HW;
        #pragma unroll
        for (int n = 0; n < 4; ++n) xls[n][o] = fb_[pix[n]];
    }
    __syncthreads();

    float h0 = b1[o], h1 = h0, h2 = h0, h3 = h0;
    const float* wr = w1 + o * CH;
    for (int c = 0; c < CH; ++c) {
        float w = wr[c];
        h0 = fmaf(w, xls[0][c], h0);
        h1 = fmaf(w, xls[1][c], h1);
        h2 = fmaf(w, xls[2][c], h2);
        h3 = fmaf(w, xls[3][c], h3);
    }
    float wsum = wv[0] + wv[1] + wv[2] + wv[3];
    hmix[o] = wv[0] * gelu_exact(h0) + wv[1] * gelu_exact(h1) +
              wv[2] * gelu_exact(h2) + wv[3] * gelu_exact(h3);
    __syncthreads();

    float acc = b2[o] * wsum;
    const float* w2r = w2 + o * CH;
    for (int c = 0; c < CH; ++c) acc = fmaf(w2r[c], hmix[c], acc);
    out[2 * TOT * 2 + 2 * TOT + ((size_t)b * TOT + s * KSEL + k) * CH + o] = acc;
}

// ---------------- host ----------------
extern "C" void kernel_launch(void* const* d_in, const int* in_sizes, int n_in,
                              void* d_out, int out_size, void* d_ws, size_t ws_size,
                              hipStream_t stream)
{
    const float* fm[4] = {(const float*)d_in[0], (const float*)d_in[1],
                          (const float*)d_in[2], (const float*)d_in[3]};
    const float* rw1 = (const float*)d_in[4];
    const float* rb1 = (const float*)d_in[5];
    const float* rw2 = (const float*)d_in[6];
    const float* rb2 = (const float*)d_in[7];
    const float* fw1 = (const float*)d_in[8];
    const float* fb1 = (const float*)d_in[9];
    const float* fw2 = (const float*)d_in[10];
    const float* fb2 = (const float*)d_in[11];

    float* ws = (float*)d_ws;
    float* rel   = ws;                              // 696320 (all scales)
    float* mask  = ws + 696320;                     // 696320 (all scales)
    float* lval  = ws + 1392640;                    // 8*CAP
    int*   lidx  = (int*)(ws + 1425408);            // 8*CAP
    int*   counts= (int*)(ws + 1458176);            // 8
    float* tv    = ws + 1458184;                    // 8*KSEL
    int*   ti    = (int*)(ws + 1462280);            // 8*KSEL
    unsigned short* wfrag = (unsigned short*)(ws + 1466376); // 49152 u16

    hipMemsetAsync(counts, 0, 8 * sizeof(int), stream);
    wconv_kernel<<<64, 256, 0, stream>>>(rw1, wfrag);
    rel_mfma_kernel<<<256, 1024, 0, stream>>>(fm[0], fm[1], fm[2], fm[3],
                                              wfrag, rb1, rw2, rb2, rel);

    nms_init_all<<<680, 256, 0, stream>>>(rel, mask);
    nms_fused_all<<<680, 256, 0, stream>>>(rel, mask, 0, lval, lidx, counts);
    nms_fused_all<<<680, 256, 0, stream>>>(rel, mask, 1, lval, lidx, counts);

    sort_topk_kernel<<<8, 1024, 0, stream>>>(lval, lidx, counts, tv, ti);
    coords_kernel<<<16, 256, 0, stream>>>(tv, ti, (float*)d_out);
    feats_kernel<<<4096, 128, 0, stream>>>(fm[0], fm[1], fm[2], fm[3],
                                           fw1, fb1, fw2, fb2, ti, (float*)d_out);
}

// Round 22
// 498.110 us; speedup vs baseline: 1.1434x; 1.1434x over previous
//
#include <hip/hip_runtime.h>
#include <math.h>

#define CH 128
#define KSEL 512
#define CAP 4096
#define TOT 2048   // 4*KSEL
#define TS 32      // NMS tile
#define NEG_INF (-__builtin_inff())

typedef short s8v __attribute__((ext_vector_type(8)));   // 8 bf16 (4 VGPRs)
typedef float f4v __attribute__((ext_vector_type(4)));   // MFMA acc

__device__ __forceinline__ float gelu_exact(float v) {
    return v * 0.5f * (1.0f + erff(v * 0.70710678118654752440f));
}

// exact 3-plane bf16 split: v = bf(h) + bf(m) + bf(l) + O(2^-24 v)
// R15 lesson: outputs are rank-ordered; rel accuracy must stay ~1e-8
// (6-term split3 passes; 3-term split2 at ~1e-5 scrambles ranks).
__device__ __forceinline__ void split3(float v, unsigned short& h,
                                       unsigned short& m, unsigned short& l)
{
    union { float f; unsigned u; } a; a.f = v;
    unsigned rh = a.u + 0x7FFFu + ((a.u >> 16) & 1u);
    h = (unsigned short)(rh >> 16);
    union { unsigned u; float f; } fh; fh.u = rh & 0xFFFF0000u;
    float r1 = v - fh.f;
    union { float f; unsigned u; } bu; bu.f = r1;
    unsigned rm = bu.u + 0x7FFFu + ((bu.u >> 16) & 1u);
    m = (unsigned short)(rm >> 16);
    union { unsigned u; float f; } fm2; fm2.u = rm & 0xFFFF0000u;
    float r2 = r1 - fm2.f;
    union { float f; unsigned u; } cu; cu.f = r2;
    unsigned rl = cu.u + 0x7FFFu + ((cu.u >> 16) & 1u);
    l = (unsigned short)(rl >> 16);
}

// ---------------- W1 -> 3-plane bf16 A-fragments (verbatim, verified) ----------------
__global__ __launch_bounds__(256) void wconv_kernel(const float* __restrict__ w1,
                                                    unsigned short* __restrict__ wfrag)
{
    for (int e = blockIdx.x * 256 + threadIdx.x; e < 49152; e += gridDim.x * 256) {
        int fid = e >> 9;
        int r = e & 511;
        int lane = r >> 3;
        int el = r & 7;
        int plane = fid % 3;
        int fq = fid / 3;
        int kc = fq >> 3, ot = fq & 7;
        int och = ot * 16 + (lane & 15);
        int k = kc * 32 + ((lane >> 4) << 3) + el;
        unsigned short h, m, l;
        split3(w1[och * CH + k], h, m, l);
        wfrag[e] = (plane == 0) ? h : (plane == 1) ? m : l;
    }
}

// ---------------- reliability head via split-bf16 MFMA (R16-verified, 254us) ----------
// Register-capped at 2 waves/SIMD (128 VGPR + 64 AGPR = 192/wave; pool=512/lane).
// R17-R21 all regressed trying to escape this point (l-from-global, merged NMS,
// reg prefetch, 16-px waves, LDS staging) — keep this exact structure.
__global__ __launch_bounds__(512) void rel_mfma_kernel(
    const float* __restrict__ fm0, const float* __restrict__ fm1,
    const float* __restrict__ fm2, const float* __restrict__ fm3,
    const unsigned short* __restrict__ wfrag,
    const float* __restrict__ b1, const float* __restrict__ w2,
    const float* __restrict__ b2, float* __restrict__ rel)
{
    __shared__ uint4 WfQ[6144];            // 96 KB W fragments
    __shared__ float w2s[128], b1s[128];
    unsigned short* Wf = (unsigned short*)WfQ;

    const int tid = threadIdx.x;
    {
        const uint4* src = (const uint4*)wfrag;
        for (int i = tid; i < 6144; i += 512) WfQ[i] = src[i];
    }
    if (tid < 128) { w2s[tid] = w2[tid]; b1s[tid] = b1[tid]; }
    __syncthreads();

    const float* fms[4] = {fm0, fm1, fm2, fm3};
    const int pre1 = 2048, pre2 = 2560, pre3 = 2688;
    const int relo[4] = {0, 524288, 655360, 688128};
    const float b2v = b2[0];

    const int lane = tid & 63;
    const int j = lane & 15;
    const int g8 = (lane >> 4) << 3;
    const int w = tid >> 6;

    for (int T = blockIdx.x; T < 2720; T += gridDim.x) {
        int s = (T >= pre1) + (T >= pre2) + (T >= pre3);
        int t2 = T - ((s == 0) ? 0 : (s == 1) ? pre1 : (s == 2) ? pre2 : pre3);
        int Wd = 512 >> s, HW = Wd * Wd;
        int p0 = t2 * 256 + w * 32;
        int b = (p0 >= HW) ? 1 : 0;
        int pb = p0 - b * HW;
        const float* fp = fms[s] + (size_t)b * CH * HW;
        int rr = Wd >> 6; if (rr < 1) rr = 1;

        const float* pxp = fp + pb + 2 * j;

        f4v acc[8][2];
        #pragma unroll
        for (int ot = 0; ot < 8; ++ot)
            #pragma unroll
            for (int st = 0; st < 2; ++st) {
                acc[ot][st][0] = 0.f; acc[ot][st][1] = 0.f;
                acc[ot][st][2] = 0.f; acc[ot][st][3] = 0.f;
            }

        #pragma unroll 1   // REAL loop: prevents load hoisting -> no spill (R14)
        for (int kc = 0; kc < 4; ++kc) {
            float2 xv[8];
            #pragma unroll
            for (int e = 0; e < 8; ++e)
                xv[e] = *(const float2*)(pxp + (size_t)(kc * 32 + g8 + e) * HW);

            s8v bh0, bm0, bl0, bh1, bm1, bl1;
            #pragma unroll
            for (int e = 0; e < 8; ++e) {
                unsigned short h, m, l;
                split3(xv[e].x, h, m, l);
                bh0[e] = (short)h; bm0[e] = (short)m; bl0[e] = (short)l;
                split3(xv[e].y, h, m, l);
                bh1[e] = (short)h; bm1[e] = (short)m; bl1[e] = (short)l;
            }
            #pragma unroll
            for (int ot = 0; ot < 8; ++ot) {
                const unsigned short* fb = Wf + (((kc << 3) + ot) * 3) * 512 + (lane << 3);
                s8v ah = *(const s8v*)fb;
                s8v am = *(const s8v*)(fb + 512);
                s8v al = *(const s8v*)(fb + 1024);
                acc[ot][0] = __builtin_amdgcn_mfma_f32_16x16x32_bf16(ah, bh0, acc[ot][0], 0, 0, 0);
                acc[ot][0] = __builtin_amdgcn_mfma_f32_16x16x32_bf16(ah, bm0, acc[ot][0], 0, 0, 0);
                acc[ot][0] = __builtin_amdgcn_mfma_f32_16x16x32_bf16(am, bh0, acc[ot][0], 0, 0, 0);
                acc[ot][0] = __builtin_amdgcn_mfma_f32_16x16x32_bf16(am, bm0, acc[ot][0], 0, 0, 0);
                acc[ot][0] = __builtin_amdgcn_mfma_f32_16x16x32_bf16(ah, bl0, acc[ot][0], 0, 0, 0);
                acc[ot][0] = __builtin_amdgcn_mfma_f32_16x16x32_bf16(al, bh0, acc[ot][0], 0, 0, 0);
                acc[ot][1] = __builtin_amdgcn_mfma_f32_16x16x32_bf16(ah, bh1, acc[ot][1], 0, 0, 0);
                acc[ot][1] = __builtin_amdgcn_mfma_f32_16x16x32_bf16(ah, bm1, acc[ot][1], 0, 0, 0);
                acc[ot][1] = __builtin_amdgcn_mfma_f32_16x16x32_bf16(am, bh1, acc[ot][1], 0, 0, 0);
                acc[ot][1] = __builtin_amdgcn_mfma_f32_16x16x32_bf16(am, bm1, acc[ot][1], 0, 0, 0);
                acc[ot][1] = __builtin_amdgcn_mfma_f32_16x16x32_bf16(ah, bl1, acc[ot][1], 0, 0, 0);
                acc[ot][1] = __builtin_amdgcn_mfma_f32_16x16x32_bf16(al, bh1, acc[ot][1], 0, 0, 0);
            }
        }

        // epilogue: C/D map (HW-verified): col = lane&15, row = (lane>>4)*4 + r
        float part0 = 0.f, part1 = 0.f;
        #pragma unroll
        for (int ot = 0; ot < 8; ++ot) {
            #pragma unroll
            for (int r = 0; r < 4; ++r) {
                int och = ot * 16 + ((lane >> 4) << 2) + r;
                float wv = w2s[och], bv = b1s[och];
                part0 += wv * gelu_exact(acc[ot][0][r] + bv);
                part1 += wv * gelu_exact(acc[ot][1][r] + bv);
            }
        }
        part0 += __shfl_xor(part0, 16);
        part0 += __shfl_xor(part0, 32);
        part1 += __shfl_xor(part1, 16);
        part1 += __shfl_xor(part1, 32);
        if (lane < 16) {
            int p0x = pb + 2 * lane;
            int y0 = p0x / Wd, x0 = p0x - y0 * Wd;
            int p1x = p0x + 1;
            int y1 = p1x / Wd, x1 = p1x - y1 * Wd;
            bool in0 = (y0 >= rr) && (y0 < Wd - rr) && (x0 >= rr) && (x0 < Wd - rr);
            bool in1 = (y1 >= rr) && (y1 < Wd - rr) && (x1 >= rr) && (x1 < Wd - rr);
            float2 o;
            o.x = in0 ? (part0 + b2v) : NEG_INF;
            o.y = in1 ? (part1 + b2v) : NEG_INF;
            *(float2*)&rel[relo[s] + b * HW + p0x] = o;
        }
    }
}

// ---------------- multi-scale NMS block decode ----------------
// tiles/scale: s0 512, s1 128, s2 32, s3 8 -> 680 blocks per stage
__device__ __forceinline__ void nms_decode(int blk, int& s, int& b, int& ty, int& tx,
                                           int& Wd, int& HW, int& r, int& ro)
{
    s = (blk >= 512) + (blk >= 640) + (blk >= 672);
    int t2 = blk - ((s == 0) ? 0 : (s == 1) ? 512 : (s == 2) ? 640 : 672);
    Wd = 512 >> s; HW = Wd * Wd;
    int tpb = (Wd / TS) * (Wd / TS);
    b = t2 / tpb;
    int t = t2 - b * tpb;
    ty = t / (Wd / TS); tx = t - ty * (Wd / TS);
    r = Wd >> 6; if (r < 1) r = 1;
    ro = (s == 0) ? 0 : (s == 1) ? 524288 : (s == 2) ? 655360 : 688128;
}

// init: mask = (rel == maxpool_r(rel))  [R16-verified]
__global__ __launch_bounds__(256) void nms_init_all(
    const float* __restrict__ rel, float* __restrict__ mask)
{
    int s, b, ty, tx, W, HW, r, ro;
    nms_decode(blockIdx.x, s, b, ty, tx, W, HW, r, ro);
    int H = W;
    int L = TS + 2 * r;
    __shared__ float wtile[48][49];
    __shared__ float t1[48][49];
    const float* wp = rel + ro + (size_t)b * HW;
    for (int idx = threadIdx.x; idx < L * L; idx += 256) {
        int i = idx / L, j = idx - i * L;
        int gy = min(max(ty * TS - r + i, 0), H - 1);
        int gx = min(max(tx * TS - r + j, 0), W - 1);
        wtile[i][j] = wp[gy * W + gx];
    }
    __syncthreads();
    for (int idx = threadIdx.x; idx < L * TS; idx += 256) {
        int i = idx / TS, j = idx - i * TS;
        float m = wtile[i][j];
        for (int d = 1; d <= 2 * r; ++d) m = fmaxf(m, wtile[i][j + d]);
        t1[i][j] = m;
    }
    __syncthreads();
    for (int idx = threadIdx.x; idx < TS * TS; idx += 256) {
        int i = idx / TS, j = idx - i * TS;
        float m = t1[i][j];
        for (int d = 1; d <= 2 * r; ++d) m = fmaxf(m, t1[i + d][j]);
        mask[ro + (size_t)b * HW + (ty * TS + i) * W + (tx * TS + j)] =
            (wtile[i + r][j + r] == m) ? 1.0f : 0.0f;
    }
}

// fused iterA+iterB (R16-verified); optional compact
__global__ __launch_bounds__(256) void nms_fused_all(
    const float* __restrict__ rel, float* __restrict__ mask, int do_compact,
    float* __restrict__ lval, int* __restrict__ lidx, int* __restrict__ counts)
{
    int s, b, ty, tx, W, HW, r, ro;
    nms_decode(blockIdx.x, s, b, ty, tx, W, HW, r, ro);
    int H = W;
    int L = TS + 4 * r;                 // <= 64
    int gy0 = ty * TS - 2 * r, gx0 = tx * TS - 2 * r;
    __shared__ float A[64][65], B[64][65], C[64][65];
    const float* mp = mask + ro + (size_t)b * HW;
    const float* rp = rel + ro + (size_t)b * HW;

    for (int idx = threadIdx.x; idx < L * L; idx += 256) {
        int i = idx / L, j = idx - i * L;
        int gy = min(max(gy0 + i, 0), H - 1);
        int gx = min(max(gx0 + j, 0), W - 1);
        A[i][j] = mp[gy * W + gx];
    }
    __syncthreads();
    int w1c = L - 2 * r;
    for (int idx = threadIdx.x; idx < L * w1c; idx += 256) {
        int i = idx / w1c, j = idx - i * w1c + r;
        float m = A[i][j - r];
        for (int d = 1; d <= 2 * r; ++d) m = fmaxf(m, A[i][j - r + d]);
        B[i][j] = m;
    }
    __syncthreads();
    for (int idx = threadIdx.x; idx < w1c * w1c; idx += 256) {
        int i = idx / w1c + r, j = idx % w1c + r;
        float m = B[i - r][j];
        for (int d = 1; d <= 2 * r; ++d) m = fmaxf(m, B[i - r + d][j]);
        C[i][j] = m;
    }
    float mreg[4];
    #pragma unroll
    for (int k = 0; k < 4; ++k) {
        int idx = threadIdx.x + k * 256;
        int i = idx >> 5, j = idx & 31;
        mreg[k] = A[2 * r + i][2 * r + j];
    }
    __syncthreads();
    for (int idx = threadIdx.x; idx < w1c * w1c; idx += 256) {
        int i = idx / w1c + r, j = idx % w1c + r;
        int gy = min(max(gy0 + i, 0), H - 1);
        int gx = min(max(gx0 + j, 0), W - 1);
        B[i][j] = (C[i][j] > 0.f) ? NEG_INF : rp[gy * W + gx];
    }
    __syncthreads();
    for (int idx = threadIdx.x; idx < w1c * TS; idx += 256) {
        int i = idx / TS + r, j = idx % TS + 2 * r;
        float m = B[i][j - r];
        for (int d = 1; d <= 2 * r; ++d) m = fmaxf(m, B[i][j - r + d]);
        A[i][j] = m;
    }
    __syncthreads();
    #pragma unroll
    for (int k = 0; k < 4; ++k) {
        int idx = threadIdx.x + k * 256;
        int i = idx >> 5, j = idx & 31;
        int ci = 2 * r + i, cj = 2 * r + j;
        float m = A[ci - r][cj];
        for (int d = 1; d <= 2 * r; ++d) m = fmaxf(m, A[ci - r + d][cj]);
        bool supp = C[ci][cj] > 0.f;
        bool newm = (B[ci][cj] == m) && !supp;
        bool fin = (mreg[k] > 0.f) || newm;
        int gy = ty * TS + i, gx = tx * TS + j;
        size_t g = ro + (size_t)b * HW + gy * W + gx;
        if (!do_compact) {
            mask[g] = fin ? 1.f : 0.f;
        } else if (fin) {
            float v = rp[gy * W + gx];
            if (!isinf(v)) {
                int bs = b * 4 + s;
                int slot = atomicAdd(&counts[bs], 1);
                if (slot < CAP) { lval[bs * CAP + slot] = v; lidx[bs * CAP + slot] = gy * W + gx; }
            }
        }
    }
}

// ---------------- per-(b,scale) bitonic sort + top-K ----------------
__global__ __launch_bounds__(1024) void sort_topk_kernel(
    const float* __restrict__ lval, const int* __restrict__ lidx,
    const int* __restrict__ counts, float* __restrict__ tv, int* __restrict__ ti)
{
    __shared__ float sv[CAP];
    __shared__ int   si[CAP];
    int bs = blockIdx.x;
    int M = counts[bs]; if (M > CAP) M = CAP;
    for (int i = threadIdx.x; i < CAP; i += 1024) {
        if (i < M) { sv[i] = lval[bs * CAP + i]; si[i] = lidx[bs * CAP + i]; }
        else       { sv[i] = NEG_INF;            si[i] = 0x7FFFFFFF; }
    }
    __syncthreads();
    for (int k = 2; k <= CAP; k <<= 1) {
        for (int j = k >> 1; j > 0; j >>= 1) {
            for (int t = threadIdx.x; t < CAP; t += 1024) {
                int p = t ^ j;
                if (p > t) {
                    float va = sv[t], vb = sv[p];
                    int   ia = si[t], ib = si[p];
                    bool aBefore = (va > vb) || (va == vb && ia < ib);
                    bool up = ((t & k) == 0);
                    if (up ? !aBefore : aBefore) {
                        sv[t] = vb; sv[p] = va; si[t] = ib; si[p] = ia;
                    }
                }
            }
            __syncthreads();
        }
    }
    for (int j = threadIdx.x; j < KSEL; j += 1024) {
        if (j < M) { tv[bs * KSEL + j] = sv[j]; ti[bs * KSEL + j] = si[j]; }
        else       { tv[bs * KSEL + j] = NEG_INF; ti[bs * KSEL + j] = j - M; }
    }
}

// ---------------- coords + reliability outputs ----------------
__global__ __launch_bounds__(256) void coords_kernel(
    const float* __restrict__ tv, const int* __restrict__ ti, float* __restrict__ out)
{
    int gid = blockIdx.x * blockDim.x + threadIdx.x;
    if (gid >= 8 * KSEL) return;
    int bs = gid / KSEL, k = gid - bs * KSEL;
    int b = bs >> 2, s = bs & 3;
    int W = 512 >> s;
    int idx = ti[gid];
    int y = idx / W, x = idx - y * W;
    float nx = (float)x / (float)(W - 1) * 2.0f - 1.0f;
    float ny = (float)y / (float)(W - 1) * 2.0f - 1.0f;
    int pos = s * KSEL + k;
    out[((size_t)b * TOT + pos) * 2 + 0] = nx;
    out[((size_t)b * TOT + pos) * 2 + 1] = ny;
    out[2 * TOT * 2 + (size_t)b * TOT + pos] = tv[gid];
}

// ---------------- gathered projection head + bilinear combine ----------------
__global__ __launch_bounds__(128) void feats_kernel(
    const float* __restrict__ fm0, const float* __restrict__ fm1,
    const float* __restrict__ fm2, const float* __restrict__ fm3,
    const float* __restrict__ w1, const float* __restrict__ b1,
    const float* __restrict__ w2, const float* __restrict__ b2,
    const int* __restrict__ ti, float* __restrict__ out)
{
    int blk = blockIdx.x;             // (b*4+s)*KSEL + k
    int bs = blk / KSEL, k = blk - bs * KSEL;
    int b = bs >> 2, s = bs & 3;
    int W = 512 >> s, H = W, HW = H * W;
    const float* fm = (s == 0) ? fm0 : (s == 1) ? fm1 : (s == 2) ? fm2 : fm3;

    int idx = ti[bs * KSEL + k];
    int yi0 = idx / W, xi0 = idx - yi0 * W;
    float nx = (float)xi0 / (float)(W - 1) * 2.0f - 1.0f;
    float ny = (float)yi0 / (float)(H - 1) * 2.0f - 1.0f;
    float ix = ((nx + 1.0f) * (float)W - 1.0f) * 0.5f;
    float iy = ((ny + 1.0f) * (float)H - 1.0f) * 0.5f;
    float x0 = floorf(ix), y0 = floorf(iy);
    float x1 = x0 + 1.0f,  y1 = y0 + 1.0f;
    float wx1 = ix - x0, wy1 = iy - y0;

    float xs[4]  = {x0, x1, x0, x1};
    float ysv[4] = {y0, y0, y1, y1};
    float wn[4]  = {(1.0f - wx1) * (1.0f - wy1), wx1 * (1.0f - wy1),
                    (1.0f - wx1) * wy1,          wx1 * wy1};
    int pix[4]; float wv[4];
    #pragma unroll
    for (int n = 0; n < 4; ++n) {
        bool valid = (xs[n] >= 0.0f) && (xs[n] <= (float)(W - 1)) &&
                     (ysv[n] >= 0.0f) && (ysv[n] <= (float)(H - 1));
        int xc = (int)fminf(fmaxf(xs[n], 0.0f), (float)(W - 1));
        int yc = (int)fminf(fmaxf(ysv[n], 0.0f), (float)(H - 1));
        pix[n] = yc * W + xc;
        wv[n] = valid ? wn[n] : 0.0f;
    }

    __shared__ float xls[4][CH];
    __shared__ float hmix[CH];
    int o = threadIdx.x;
    {
        const float* fb_ = fm + ((size_t)b * CH + o) * HW;
        #pragma unroll
        for (int n = 0; n < 4; ++n) xls[n][o] = fb_[pix[n]];
    }
    __syncthreads();

    float h0 = b1[o], h1 = h0, h2 = h0, h3 = h0;
    const float* wr = w1 + o * CH;
    for (int c = 0; c < CH; ++c) {
        float w = wr[c];
        h0 = fmaf(w, xls[0][c], h0);
        h1 = fmaf(w, xls[1][c], h1);
        h2 = fmaf(w, xls[2][c], h2);
        h3 = fmaf(w, xls[3][c], h3);
    }
    float wsum = wv[0] + wv[1] + wv[2] + wv[3];
    hmix[o] = wv[0] * gelu_exact(h0) + wv[1] * gelu_exact(h1) +
              wv[2] * gelu_exact(h2) + wv[3] * gelu_exact(h3);
    __syncthreads();

    float acc = b2[o] * wsum;
    const float* w2r = w2 + o * CH;
    for (int c = 0; c < CH; ++c) acc = fmaf(w2r[c], hmix[c], acc);
    out[2 * TOT * 2 + 2 * TOT + ((size_t)b * TOT + s * KSEL + k) * CH + o] = acc;
}

// ---------------- host ----------------
extern "C" void kernel_launch(void* const* d_in, const int* in_sizes, int n_in,
                              void* d_out, int out_size, void* d_ws, size_t ws_size,
                              hipStream_t stream)
{
    const float* fm[4] = {(const float*)d_in[0], (const float*)d_in[1],
                          (const float*)d_in[2], (const float*)d_in[3]};
    const float* rw1 = (const float*)d_in[4];
    const float* rb1 = (const float*)d_in[5];
    const float* rw2 = (const float*)d_in[6];
    const float* rb2 = (const float*)d_in[7];
    const float* fw1 = (const float*)d_in[8];
    const float* fb1 = (const float*)d_in[9];
    const float* fw2 = (const float*)d_in[10];
    const float* fb2 = (const float*)d_in[11];

    float* ws = (float*)d_ws;
    float* rel   = ws;                              // 696320 (all scales)
    float* mask  = ws + 696320;                     // 696320 (all scales)
    float* lval  = ws + 1392640;                    // 8*CAP
    int*   lidx  = (int*)(ws + 1425408);            // 8*CAP
    int*   counts= (int*)(ws + 1458176);            // 8
    float* tv    = ws + 1458184;                    // 8*KSEL
    int*   ti    = (int*)(ws + 1462280);            // 8*KSEL
    unsigned short* wfrag = (unsigned short*)(ws + 1466376); // 49152 u16

    hipMemsetAsync(counts, 0, 8 * sizeof(int), stream);
    wconv_kernel<<<64, 256, 0, stream>>>(rw1, wfrag);
    rel_mfma_kernel<<<256, 512, 0, stream>>>(fm[0], fm[1], fm[2], fm[3],
                                             wfrag, rb1, rw2, rb2, rel);

    nms_init_all<<<680, 256, 0, stream>>>(rel, mask);
    nms_fused_all<<<680, 256, 0, stream>>>(rel, mask, 0, lval, lidx, counts);
    nms_fused_all<<<680, 256, 0, stream>>>(rel, mask, 1, lval, lidx, counts);

    sort_topk_kernel<<<8, 1024, 0, stream>>>(lval, lidx, counts, tv, ti);
    coords_kernel<<<16, 256, 0, stream>>>(tv, ti, (float*)d_out);
    feats_kernel<<<4096, 128, 0, stream>>>(fm[0], fm[1], fm[2], fm[3],
                                           fw1, fb1, fw2, fb2, ti, (float*)d_out);
}

// Round 23
// 493.272 us; speedup vs baseline: 1.1546x; 1.0098x over previous
//
#include <hip/hip_runtime.h>
#include <hip/hip_bf16.h>
#include <math.h>

#define CH 128
#define KSEL 512
#define CAP 4096
#define TOT 2048   // 4*KSEL
#define TS 32      // NMS tile
#define NEG_INF (-__builtin_inff())

typedef short s8v __attribute__((ext_vector_type(8)));   // 8 bf16 (4 VGPRs)
typedef float f4v __attribute__((ext_vector_type(4)));   // MFMA acc

__device__ __forceinline__ float gelu_exact(float v) {
    return v * 0.5f * (1.0f + erff(v * 0.70710678118654752440f));
}

// exact 3-plane bf16 split via HW cvt: v = bf(h) + bf(m) + bf(l) + O(2^-24 v)
// R15 lesson: outputs are rank-ordered; rel accuracy must stay ~1e-8.
// RTNE native cvt == the old manual emulation (tie diffs absorbed by m/l planes).
__device__ __forceinline__ void split3(float v, unsigned short& h,
                                       unsigned short& m, unsigned short& l)
{
    union BU { __hip_bfloat16 b; unsigned short u; };
    __hip_bfloat16 hb = __float2bfloat16(v);
    BU x; x.b = hb; h = x.u;
    float r1 = v - __bfloat162float(hb);
    __hip_bfloat16 mb = __float2bfloat16(r1);
    BU y; y.b = mb; m = y.u;
    float r2 = r1 - __bfloat162float(mb);
    __hip_bfloat16 lb = __float2bfloat16(r2);
    BU z; z.b = lb; l = z.u;
}

// ---------------- W1 -> 3-plane bf16 A-fragments (verified layout) ----------------
__global__ __launch_bounds__(256) void wconv_kernel(const float* __restrict__ w1,
                                                    unsigned short* __restrict__ wfrag)
{
    for (int e = blockIdx.x * 256 + threadIdx.x; e < 49152; e += gridDim.x * 256) {
        int fid = e >> 9;
        int r = e & 511;
        int lane = r >> 3;
        int el = r & 7;
        int plane = fid % 3;
        int fq = fid / 3;
        int kc = fq >> 3, ot = fq & 7;
        int och = ot * 16 + (lane & 15);
        int k = kc * 32 + ((lane >> 4) << 3) + el;
        unsigned short h, m, l;
        split3(w1[och * CH + k], h, m, l);
        wfrag[e] = (plane == 0) ? h : (plane == 1) ? m : l;
    }
}

// ---------------- reliability head via split-bf16 MFMA (R16-verified, 254us) ----------
// Register-capped at 2 waves/SIMD (128 VGPR + 64 AGPR = 192/wave; pool=512/lane).
// R17-R21 all regressed trying to escape this point (l-from-global, merged NMS,
// reg prefetch, 16-px waves, LDS staging) — keep this exact structure.
__global__ __launch_bounds__(512) void rel_mfma_kernel(
    const float* __restrict__ fm0, const float* __restrict__ fm1,
    const float* __restrict__ fm2, const float* __restrict__ fm3,
    const unsigned short* __restrict__ wfrag,
    const float* __restrict__ b1, const float* __restrict__ w2,
    const float* __restrict__ b2, float* __restrict__ rel)
{
    __shared__ uint4 WfQ[6144];            // 96 KB W fragments
    __shared__ float w2s[128], b1s[128];
    unsigned short* Wf = (unsigned short*)WfQ;

    const int tid = threadIdx.x;
    {
        const uint4* src = (const uint4*)wfrag;
        for (int i = tid; i < 6144; i += 512) WfQ[i] = src[i];
    }
    if (tid < 128) { w2s[tid] = w2[tid]; b1s[tid] = b1[tid]; }
    __syncthreads();

    const float* fms[4] = {fm0, fm1, fm2, fm3};
    const int pre1 = 2048, pre2 = 2560, pre3 = 2688;
    const int relo[4] = {0, 524288, 655360, 688128};
    const float b2v = b2[0];

    const int lane = tid & 63;
    const int j = lane & 15;
    const int g8 = (lane >> 4) << 3;
    const int w = tid >> 6;

    for (int T = blockIdx.x; T < 2720; T += gridDim.x) {
        int s = (T >= pre1) + (T >= pre2) + (T >= pre3);
        int t2 = T - ((s == 0) ? 0 : (s == 1) ? pre1 : (s == 2) ? pre2 : pre3);
        int Wd = 512 >> s, HW = Wd * Wd;
        int p0 = t2 * 256 + w * 32;
        int b = (p0 >= HW) ? 1 : 0;
        int pb = p0 - b * HW;
        const float* fp = fms[s] + (size_t)b * CH * HW;
        int rr = Wd >> 6; if (rr < 1) rr = 1;

        const float* pxp = fp + pb + 2 * j;

        f4v acc[8][2];
        #pragma unroll
        for (int ot = 0; ot < 8; ++ot)
            #pragma unroll
            for (int st = 0; st < 2; ++st) {
                acc[ot][st][0] = 0.f; acc[ot][st][1] = 0.f;
                acc[ot][st][2] = 0.f; acc[ot][st][3] = 0.f;
            }

        #pragma unroll 1   // REAL loop: prevents load hoisting -> no spill (R14)
        for (int kc = 0; kc < 4; ++kc) {
            float2 xv[8];
            #pragma unroll
            for (int e = 0; e < 8; ++e)
                xv[e] = *(const float2*)(pxp + (size_t)(kc * 32 + g8 + e) * HW);

            s8v bh0, bm0, bl0, bh1, bm1, bl1;
            #pragma unroll
            for (int e = 0; e < 8; ++e) {
                unsigned short h, m, l;
                split3(xv[e].x, h, m, l);
                bh0[e] = (short)h; bm0[e] = (short)m; bl0[e] = (short)l;
                split3(xv[e].y, h, m, l);
                bh1[e] = (short)h; bm1[e] = (short)m; bl1[e] = (short)l;
            }
            #pragma unroll
            for (int ot = 0; ot < 8; ++ot) {
                const unsigned short* fb = Wf + (((kc << 3) + ot) * 3) * 512 + (lane << 3);
                s8v ah = *(const s8v*)fb;
                s8v am = *(const s8v*)(fb + 512);
                s8v al = *(const s8v*)(fb + 1024);
                acc[ot][0] = __builtin_amdgcn_mfma_f32_16x16x32_bf16(ah, bh0, acc[ot][0], 0, 0, 0);
                acc[ot][0] = __builtin_amdgcn_mfma_f32_16x16x32_bf16(ah, bm0, acc[ot][0], 0, 0, 0);
                acc[ot][0] = __builtin_amdgcn_mfma_f32_16x16x32_bf16(am, bh0, acc[ot][0], 0, 0, 0);
                acc[ot][0] = __builtin_amdgcn_mfma_f32_16x16x32_bf16(am, bm0, acc[ot][0], 0, 0, 0);
                acc[ot][0] = __builtin_amdgcn_mfma_f32_16x16x32_bf16(ah, bl0, acc[ot][0], 0, 0, 0);
                acc[ot][0] = __builtin_amdgcn_mfma_f32_16x16x32_bf16(al, bh0, acc[ot][0], 0, 0, 0);
                acc[ot][1] = __builtin_amdgcn_mfma_f32_16x16x32_bf16(ah, bh1, acc[ot][1], 0, 0, 0);
                acc[ot][1] = __builtin_amdgcn_mfma_f32_16x16x32_bf16(ah, bm1, acc[ot][1], 0, 0, 0);
                acc[ot][1] = __builtin_amdgcn_mfma_f32_16x16x32_bf16(am, bh1, acc[ot][1], 0, 0, 0);
                acc[ot][1] = __builtin_amdgcn_mfma_f32_16x16x32_bf16(am, bm1, acc[ot][1], 0, 0, 0);
                acc[ot][1] = __builtin_amdgcn_mfma_f32_16x16x32_bf16(ah, bl1, acc[ot][1], 0, 0, 0);
                acc[ot][1] = __builtin_amdgcn_mfma_f32_16x16x32_bf16(al, bh1, acc[ot][1], 0, 0, 0);
            }
        }

        // epilogue: C/D map (HW-verified): col = lane&15, row = (lane>>4)*4 + r
        float part0 = 0.f, part1 = 0.f;
        #pragma unroll
        for (int ot = 0; ot < 8; ++ot) {
            #pragma unroll
            for (int r = 0; r < 4; ++r) {
                int och = ot * 16 + ((lane >> 4) << 2) + r;
                float wv = w2s[och], bv = b1s[och];
                part0 += wv * gelu_exact(acc[ot][0][r] + bv);
                part1 += wv * gelu_exact(acc[ot][1][r] + bv);
            }
        }
        part0 += __shfl_xor(part0, 16);
        part0 += __shfl_xor(part0, 32);
        part1 += __shfl_xor(part1, 16);
        part1 += __shfl_xor(part1, 32);
        if (lane < 16) {
            int p0x = pb + 2 * lane;
            int y0 = p0x / Wd, x0 = p0x - y0 * Wd;
            int p1x = p0x + 1;
            int y1 = p1x / Wd, x1 = p1x - y1 * Wd;
            bool in0 = (y0 >= rr) && (y0 < Wd - rr) && (x0 >= rr) && (x0 < Wd - rr);
            bool in1 = (y1 >= rr) && (y1 < Wd - rr) && (x1 >= rr) && (x1 < Wd - rr);
            float2 o;
            o.x = in0 ? (part0 + b2v) : NEG_INF;
            o.y = in1 ? (part1 + b2v) : NEG_INF;
            *(float2*)&rel[relo[s] + b * HW + p0x] = o;
        }
    }
}

// ---------------- multi-scale NMS block decode ----------------
// tiles/scale: s0 512, s1 128, s2 32, s3 8 -> 680 blocks per stage
__device__ __forceinline__ void nms_decode(int blk, int& s, int& b, int& ty, int& tx,
                                           int& Wd, int& HW, int& r, int& ro)
{
    s = (blk >= 512) + (blk >= 640) + (blk >= 672);
    int t2 = blk - ((s == 0) ? 0 : (s == 1) ? 512 : (s == 2) ? 640 : 672);
    Wd = 512 >> s; HW = Wd * Wd;
    int tpb = (Wd / TS) * (Wd / TS);
    b = t2 / tpb;
    int t = t2 - b * tpb;
    ty = t / (Wd / TS); tx = t - ty * (Wd / TS);
    r = Wd >> 6; if (r < 1) r = 1;
    ro = (s == 0) ? 0 : (s == 1) ? 524288 : (s == 2) ? 655360 : 688128;
}

// init: mask = (rel == maxpool_r(rel))  [R16-verified]
__global__ __launch_bounds__(256) void nms_init_all(
    const float* __restrict__ rel, float* __restrict__ mask)
{
    int s, b, ty, tx, W, HW, r, ro;
    nms_decode(blockIdx.x, s, b, ty, tx, W, HW, r, ro);
    int H = W;
    int L = TS + 2 * r;
    __shared__ float wtile[48][49];
    __shared__ float t1[48][49];
    const float* wp = rel + ro + (size_t)b * HW;
    for (int idx = threadIdx.x; idx < L * L; idx += 256) {
        int i = idx / L, j = idx - i * L;
        int gy = min(max(ty * TS - r + i, 0), H - 1);
        int gx = min(max(tx * TS - r + j, 0), W - 1);
        wtile[i][j] = wp[gy * W + gx];
    }
    __syncthreads();
    for (int idx = threadIdx.x; idx < L * TS; idx += 256) {
        int i = idx / TS, j = idx - i * TS;
        float m = wtile[i][j];
        for (int d = 1; d <= 2 * r; ++d) m = fmaxf(m, wtile[i][j + d]);
        t1[i][j] = m;
    }
    __syncthreads();
    for (int idx = threadIdx.x; idx < TS * TS; idx += 256) {
        int i = idx / TS, j = idx - i * TS;
        float m = t1[i][j];
        for (int d = 1; d <= 2 * r; ++d) m = fmaxf(m, t1[i + d][j]);
        mask[ro + (size_t)b * HW + (ty * TS + i) * W + (tx * TS + j)] =
            (wtile[i + r][j + r] == m) ? 1.0f : 0.0f;
    }
}

// fused iterA+iterB (R16-verified); optional compact
__global__ __launch_bounds__(256) void nms_fused_all(
    const float* __restrict__ rel, float* __restrict__ mask, int do_compact,
    float* __restrict__ lval, int* __restrict__ lidx, int* __restrict__ counts)
{
    int s, b, ty, tx, W, HW, r, ro;
    nms_decode(blockIdx.x, s, b, ty, tx, W, HW, r, ro);
    int H = W;
    int L = TS + 4 * r;                 // <= 64
    int gy0 = ty * TS - 2 * r, gx0 = tx * TS - 2 * r;
    __shared__ float A[64][65], B[64][65], C[64][65];
    const float* mp = mask + ro + (size_t)b * HW;
    const float* rp = rel + ro + (size_t)b * HW;

    for (int idx = threadIdx.x; idx < L * L; idx += 256) {
        int i = idx / L, j = idx - i * L;
        int gy = min(max(gy0 + i, 0), H - 1);
        int gx = min(max(gx0 + j, 0), W - 1);
        A[i][j] = mp[gy * W + gx];
    }
    __syncthreads();
    int w1c = L - 2 * r;
    for (int idx = threadIdx.x; idx < L * w1c; idx += 256) {
        int i = idx / w1c, j = idx - i * w1c + r;
        float m = A[i][j - r];
        for (int d = 1; d <= 2 * r; ++d) m = fmaxf(m, A[i][j - r + d]);
        B[i][j] = m;
    }
    __syncthreads();
    for (int idx = threadIdx.x; idx < w1c * w1c; idx += 256) {
        int i = idx / w1c + r, j = idx % w1c + r;
        float m = B[i - r][j];
        for (int d = 1; d <= 2 * r; ++d) m = fmaxf(m, B[i - r + d][j]);
        C[i][j] = m;
    }
    float mreg[4];
    #pragma unroll
    for (int k = 0; k < 4; ++k) {
        int idx = threadIdx.x + k * 256;
        int i = idx >> 5, j = idx & 31;
        mreg[k] = A[2 * r + i][2 * r + j];
    }
    __syncthreads();
    for (int idx = threadIdx.x; idx < w1c * w1c; idx += 256) {
        int i = idx / w1c + r, j = idx % w1c + r;
        int gy = min(max(gy0 + i, 0), H - 1);
        int gx = min(max(gx0 + j, 0), W - 1);
        B[i][j] = (C[i][j] > 0.f) ? NEG_INF : rp[gy * W + gx];
    }
    __syncthreads();
    for (int idx = threadIdx.x; idx < w1c * TS; idx += 256) {
        int i = idx / TS + r, j = idx % TS + 2 * r;
        float m = B[i][j - r];
        for (int d = 1; d <= 2 * r; ++d) m = fmaxf(m, B[i][j - r + d]);
        A[i][j] = m;
    }
    __syncthreads();
    #pragma unroll
    for (int k = 0; k < 4; ++k) {
        int idx = threadIdx.x + k * 256;
        int i = idx >> 5, j = idx & 31;
        int ci = 2 * r + i, cj = 2 * r + j;
        float m = A[ci - r][cj];
        for (int d = 1; d <= 2 * r; ++d) m = fmaxf(m, A[ci - r + d][cj]);
        bool supp = C[ci][cj] > 0.f;
        bool newm = (B[ci][cj] == m) && !supp;
        bool fin = (mreg[k] > 0.f) || newm;
        int gy = ty * TS + i, gx = tx * TS + j;
        size_t g = ro + (size_t)b * HW + gy * W + gx;
        if (!do_compact) {
            mask[g] = fin ? 1.f : 0.f;
        } else if (fin) {
            float v = rp[gy * W + gx];
            if (!isinf(v)) {
                int bs = b * 4 + s;
                int slot = atomicAdd(&counts[bs], 1);
                if (slot < CAP) { lval[bs * CAP + slot] = v; lidx[bs * CAP + slot] = gy * W + gx; }
            }
        }
    }
}

// ---------------- per-(b,scale) bitonic sort + top-K ----------------
__global__ __launch_bounds__(1024) void sort_topk_kernel(
    const float* __restrict__ lval, const int* __restrict__ lidx,
    const int* __restrict__ counts, float* __restrict__ tv, int* __restrict__ ti)
{
    __shared__ float sv[CAP];
    __shared__ int   si[CAP];
    int bs = blockIdx.x;
    int M = counts[bs]; if (M > CAP) M = CAP;
    for (int i = threadIdx.x; i < CAP; i += 1024) {
        if (i < M) { sv[i] = lval[bs * CAP + i]; si[i] = lidx[bs * CAP + i]; }
        else       { sv[i] = NEG_INF;            si[i] = 0x7FFFFFFF; }
    }
    __syncthreads();
    for (int k = 2; k <= CAP; k <<= 1) {
        for (int j = k >> 1; j > 0; j >>= 1) {
            for (int t = threadIdx.x; t < CAP; t += 1024) {
                int p = t ^ j;
                if (p > t) {
                    float va = sv[t], vb = sv[p];
                    int   ia = si[t], ib = si[p];
                    bool aBefore = (va > vb) || (va == vb && ia < ib);
                    bool up = ((t & k) == 0);
                    if (up ? !aBefore : aBefore) {
                        sv[t] = vb; sv[p] = va; si[t] = ib; si[p] = ia;
                    }
                }
            }
            __syncthreads();
        }
    }
    for (int j = threadIdx.x; j < KSEL; j += 1024) {
        if (j < M) { tv[bs * KSEL + j] = sv[j]; ti[bs * KSEL + j] = si[j]; }
        else       { tv[bs * KSEL + j] = NEG_INF; ti[bs * KSEL + j] = j - M; }
    }
}

// ---------------- coords + reliability outputs ----------------
__global__ __launch_bounds__(256) void coords_kernel(
    const float* __restrict__ tv, const int* __restrict__ ti, float* __restrict__ out)
{
    int gid = blockIdx.x * blockDim.x + threadIdx.x;
    if (gid >= 8 * KSEL) return;
    int bs = gid / KSEL, k = gid - bs * KSEL;
    int b = bs >> 2, s = bs & 3;
    int W = 512 >> s;
    int idx = ti[gid];
    int y = idx / W, x = idx - y * W;
    float nx = (float)x / (float)(W - 1) * 2.0f - 1.0f;
    float ny = (float)y / (float)(W - 1) * 2.0f - 1.0f;
    int pos = s * KSEL + k;
    out[((size_t)b * TOT + pos) * 2 + 0] = nx;
    out[((size_t)b * TOT + pos) * 2 + 1] = ny;
    out[2 * TOT * 2 + (size_t)b * TOT + pos] = tv[gid];
}

// ---------------- gathered projection head + bilinear combine ----------------
__global__ __launch_bounds__(128) void feats_kernel(
    const float* __restrict__ fm0, const float* __restrict__ fm1,
    const float* __restrict__ fm2, const float* __restrict__ fm3,
    const float* __restrict__ w1, const float* __restrict__ b1,
    const float* __restrict__ w2, const float* __restrict__ b2,
    const int* __restrict__ ti, float* __restrict__ out)
{
    int blk = blockIdx.x;             // (b*4+s)*KSEL + k
    int bs = blk / KSEL, k = blk - bs * KSEL;
    int b = bs >> 2, s = bs & 3;
    int W = 512 >> s, H = W, HW = H * W;
    const float* fm = (s == 0) ? fm0 : (s == 1) ? fm1 : (s == 2) ? fm2 : fm3;

    int idx = ti[bs * KSEL + k];
    int yi0 = idx / W, xi0 = idx - yi0 * W;
    float nx = (float)xi0 / (float)(W - 1) * 2.0f - 1.0f;
    float ny = (float)yi0 / (float)(H - 1) * 2.0f - 1.0f;
    float ix = ((nx + 1.0f) * (float)W - 1.0f) * 0.5f;
    float iy = ((ny + 1.0f) * (float)H - 1.0f) * 0.5f;
    float x0 = floorf(ix), y0 = floorf(iy);
    float x1 = x0 + 1.0f,  y1 = y0 + 1.0f;
    float wx1 = ix - x0, wy1 = iy - y0;

    float xs[4]  = {x0, x1, x0, x1};
    float ysv[4] = {y0, y0, y1, y1};
    float wn[4]  = {(1.0f - wx1) * (1.0f - wy1), wx1 * (1.0f - wy1),
                    (1.0f - wx1) * wy1,          wx1 * wy1};
    int pix[4]; float wv[4];
    #pragma unroll
    for (int n = 0; n < 4; ++n) {
        bool valid = (xs[n] >= 0.0f) && (xs[n] <= (float)(W - 1)) &&
                     (ysv[n] >= 0.0f) && (ysv[n] <= (float)(H - 1));
        int xc = (int)fminf(fmaxf(xs[n], 0.0f), (float)(W - 1));
        int yc = (int)fminf(fmaxf(ysv[n], 0.0f), (float)(H - 1));
        pix[n] = yc * W + xc;
        wv[n] = valid ? wn[n] : 0.0f;
    }

    __shared__ float xls[4][CH];
    __shared__ float hmix[CH];
    int o = threadIdx.x;
    {
        const float* fb_ = fm + ((size_t)b * CH + o) * HW;
        #pragma unroll
        for (int n = 0; n < 4; ++n) xls[n][o] = fb_[pix[n]];
    }
    __syncthreads();

    float h0 = b1[o], h1 = h0, h2 = h0, h3 = h0;
    const float* wr = w1 + o * CH;
    for (int c = 0; c < CH; ++c) {
        float w = wr[c];
        h0 = fmaf(w, xls[0][c], h0);
        h1 = fmaf(w, xls[1][c], h1);
        h2 = fmaf(w, xls[2][c], h2);
        h3 = fmaf(w, xls[3][c], h3);
    }
    float wsum = wv[0] + wv[1] + wv[2] + wv[3];
    hmix[o] = wv[0] * gelu_exact(h0) + wv[1] * gelu_exact(h1) +
              wv[2] * gelu_exact(h2) + wv[3] * gelu_exact(h3);
    __syncthreads();

    float acc = b2[o] * wsum;
    const float* w2r = w2 + o * CH;
    for (int c = 0; c < CH; ++c) acc = fmaf(w2r[c], hmix[c], acc);
    out[2 * TOT * 2 + 2 * TOT + ((size_t)b * TOT + s * KSEL + k) * CH + o] = acc;
}

// ---------------- host ----------------
extern "C" void kernel_launch(void* const* d_in, const int* in_sizes, int n_in,
                              void* d_out, int out_size, void* d_ws, size_t ws_size,
                              hipStream_t stream)
{
    const float* fm[4] = {(const float*)d_in[0], (const float*)d_in[1],
                          (const float*)d_in[2], (const float*)d_in[3]};
    const float* rw1 = (const float*)d_in[4];
    const float* rb1 = (const float*)d_in[5];
    const float* rw2 = (const float*)d_in[6];
    const float* rb2 = (const float*)d_in[7];
    const float* fw1 = (const float*)d_in[8];
    const float* fb1 = (const float*)d_in[9];
    const float* fw2 = (const float*)d_in[10];
    const float* fb2 = (const float*)d_in[11];

    float* ws = (float*)d_ws;
    float* rel   = ws;                              // 696320 (all scales)
    float* mask  = ws + 696320;                     // 696320 (all scales)
    float* lval  = ws + 1392640;                    // 8*CAP
    int*   lidx  = (int*)(ws + 1425408);            // 8*CAP
    int*   counts= (int*)(ws + 1458176);            // 8
    float* tv    = ws + 1458184;                    // 8*KSEL
    int*   ti    = (int*)(ws + 1462280);            // 8*KSEL
    unsigned short* wfrag = (unsigned short*)(ws + 1466376); // 49152 u16

    hipMemsetAsync(counts, 0, 8 * sizeof(int), stream);
    wconv_kernel<<<64, 256, 0, stream>>>(rw1, wfrag);
    rel_mfma_kernel<<<256, 512, 0, stream>>>(fm[0], fm[1], fm[2], fm[3],
                                             wfrag, rb1, rw2, rb2, rel);

    nms_init_all<<<680, 256, 0, stream>>>(rel, mask);
    nms_fused_all<<<680, 256, 0, stream>>>(rel, mask, 0, lval, lidx, counts);
    nms_fused_all<<<680, 256, 0, stream>>>(rel, mask, 1, lval, lidx, counts);

    sort_topk_kernel<<<8, 1024, 0, stream>>>(lval, lidx, counts, tv, ti);
    coords_kernel<<<16, 256, 0, stream>>>(tv, ti, (float*)d_out);
    feats_kernel<<<4096, 128, 0, stream>>>(fm[0], fm[1], fm[2], fm[3],
                                           fw1, fb1, fw2, fb2, ti, (float*)d_out);
}